// Round 4
// baseline (561.600 us; speedup 1.0000x reference)
//
#include <hip/hip_runtime.h>
#include <math.h>

// edge = a*box5(x) + b*box3(x) + c*x   (fused K5+K3 depthwise conv, zero pad)
// out  = abs(maxpool5(edge))           (maxpool pads with -inf)
// One wave (64 lanes x float4) == one full 256-px row. Each wave slides down a
// 16-row strip keeping vertical context in register rings. No LDS.
// TY=16: 8192 wave-tasks = 32 waves/CU (grid-limited exactly at HW cap).
// Rings shrunk via consume-before-insert (Cr 2-deep, Q3 3-deep) to fit 64 VGPR
// so __launch_bounds__(256,8) gives 8 waves/SIMD.

#define TY 16
#define STEPS (TY + 8)

typedef float vfloat4 __attribute__((ext_vector_type(4)));

__global__ __launch_bounds__(256, 8)
void edgepool_kernel(const float* __restrict__ xin, float* __restrict__ yout) {
    const int lane  = threadIdx.x & 63;
    const int wave  = threadIdx.x >> 6;
    const int blk   = blockIdx.x;                 // 0..2047
    const int plane = blk >> 2;                   // 0..511  (= b*64 + c)
    const int strip = ((blk & 3) << 2) | wave;    // 0..15   (4 adjacent strips/block)
    const int y0    = strip * TY;

    const float4* __restrict__ in4  = (const float4*)xin + (size_t)plane * 16384;
    vfloat4*      __restrict__ out4 = (vfloat4*)    yout + (size_t)plane * 16384;

    const float Wa = -0.01f, Wb = -0.19f, Wc = 2.2f;
    const float NINF = -INFINITY;

    float Cr[2][4];   // raw input rows (center tap, consumed 2 steps later)
    float P5[5][4];   // horizontal 5-box sums ring (needs current..current-4)
    float Q3[3][4];   // horizontal 3-box sums ring (needs current-1..current-3)
    float M5[5][4];   // horizontal 5-max of edge ring
#pragma unroll
    for (int j = 0; j < 4; ++j) {
        Cr[0][j] = Cr[1][j] = 0.f;
        Q3[0][j] = Q3[1][j] = Q3[2][j] = 0.f;
        P5[0][j] = P5[1][j] = P5[2][j] = P5[3][j] = P5[4][j] = 0.f;
        M5[0][j] = M5[1][j] = M5[2][j] = M5[3][j] = M5[4][j] = NINF;
    }

#pragma unroll
    for (int t = 0; t < STEPS; ++t) {
        const int  r   = y0 - 4 + t;                 // input row being consumed
        const bool rin = (unsigned)r < 256u;
        const int  rc  = rin ? r : (r < 0 ? 0 : 255);
        const float4 vv = in4[rc * 64 + lane];       // unconditional load (pipelinable)
        const float v0 = rin ? vv.x : 0.f;
        const float v1 = rin ? vv.y : 0.f;
        const float v2 = rin ? vv.z : 0.f;
        const float v3 = rin ? vv.w : 0.f;

        // horizontal halo from neighbor lanes (zero-pad image edges)
        float lm2 = __shfl(v2, lane - 1, 64);
        float lm1 = __shfl(v3, lane - 1, 64);
        float rp0 = __shfl(v0, lane + 1, 64);
        float rp1 = __shfl(v1, lane + 1, 64);
        lm2 = (lane == 0)  ? 0.f : lm2;
        lm1 = (lane == 0)  ? 0.f : lm1;
        rp0 = (lane == 63) ? 0.f : rp0;
        rp1 = (lane == 63) ? 0.f : rp1;

        // horizontal box sums for this row
        const float s01  = v0 + v1;
        const float s23  = v2 + v3;
        const float h3_0 = lm1 + s01;
        const float h3_1 = s01 + v2;
        const float h3_2 = v1 + s23;
        const float h3_3 = s23 + rp0;
        const float h5_0 = lm2 + h3_0 + v2;
        const float h5_1 = lm1 + s01 + s23;
        const float h5_2 = s01 + s23 + rp0;
        const float h5_3 = v1 + s23 + rp0 + rp1;

        // P5 inserts BEFORE consume (edge needs current row's h5)
        const int tp = t % 5;                        // compile-time after unroll
        P5[tp][0] = h5_0; P5[tp][1] = h5_1; P5[tp][2] = h5_2; P5[tp][3] = h5_3;

        // edge row er = r - 2 (h5 rows r-4..r, h3 rows r-3..r-1, x row r-2)
        const int  er  = r - 2;
        const bool ein = (unsigned)er < 256u;
        const int a1 = (t + 4) % 5, a2 = (t + 3) % 5, a3 = (t + 2) % 5, a4 = (t + 1) % 5;
        const int b1 = (t + 2) % 3, b2 = (t + 1) % 3, b3 = t % 3;   // rows r-1, r-2, r-3
        const int cc = t % 2;                                        // row r-2
        float e[4];
#pragma unroll
        for (int j = 0; j < 4; ++j) {
            const float S5 = P5[tp][j] + P5[a1][j] + P5[a2][j] + P5[a3][j] + P5[a4][j];
            const float S3 = Q3[b1][j] + Q3[b2][j] + Q3[b3][j];
            const float ev = fmaf(Wc, Cr[cc][j], fmaf(Wb, S3, Wa * S5));
            e[j] = ein ? ev : NINF;   // rows outside image are -inf for the maxpool
        }

        // consume done -> insert current row into Q3 / Cr (overwrites r-3 / r-2)
        Q3[b3][0] = h3_0; Q3[b3][1] = h3_1; Q3[b3][2] = h3_2; Q3[b3][3] = h3_3;
        Cr[cc][0] = v0;   Cr[cc][1] = v1;   Cr[cc][2] = v2;   Cr[cc][3] = v3;

        // horizontal 5-max of edge row (-inf pad at image edges)
        float el2 = __shfl(e[2], lane - 1, 64);
        float el1 = __shfl(e[3], lane - 1, 64);
        float er0 = __shfl(e[0], lane + 1, 64);
        float er1 = __shfl(e[1], lane + 1, 64);
        el2 = (lane == 0)  ? NINF : el2;
        el1 = (lane == 0)  ? NINF : el1;
        er0 = (lane == 63) ? NINF : er0;
        er1 = (lane == 63) ? NINF : er1;

        M5[tp][0] = fmaxf(fmaxf(fmaxf(el2, el1), fmaxf(e[0], e[1])), e[2]);
        M5[tp][1] = fmaxf(fmaxf(fmaxf(el1, e[0]), fmaxf(e[1], e[2])), e[3]);
        M5[tp][2] = fmaxf(fmaxf(fmaxf(e[0], e[1]), fmaxf(e[2], e[3])), er0);
        M5[tp][3] = fmaxf(fmaxf(fmaxf(e[1], e[2]), fmaxf(e[3], er0)), er1);

        // output row o = r - 4 (vertical 5-max over M5 ring), valid from t>=8
        if (t >= 8) {   // compile-time predicate after unroll
            const int o = r - 4;
            vfloat4 ov;
            ov.x = fabsf(fmaxf(fmaxf(fmaxf(M5[0][0], M5[1][0]), fmaxf(M5[2][0], M5[3][0])), M5[4][0]));
            ov.y = fabsf(fmaxf(fmaxf(fmaxf(M5[0][1], M5[1][1]), fmaxf(M5[2][1], M5[3][1])), M5[4][1]));
            ov.z = fabsf(fmaxf(fmaxf(fmaxf(M5[0][2], M5[1][2]), fmaxf(M5[2][2], M5[3][2])), M5[4][2]));
            ov.w = fabsf(fmaxf(fmaxf(fmaxf(M5[0][3], M5[1][3]), fmaxf(M5[2][3], M5[3][3])), M5[4][3]));
            __builtin_nontemporal_store(ov, &out4[o * 64 + lane]);
        }
    }
}

extern "C" void kernel_launch(void* const* d_in, const int* in_sizes, int n_in,
                              void* d_out, int out_size, void* d_ws, size_t ws_size,
                              hipStream_t stream) {
    const float* x   = (const float*)d_in[0];
    float*       out = (float*)d_out;
    // 512 planes x 16 strips = 8192 wave-tasks; 4 waves/block -> 2048 blocks
    // = 8 blocks/CU = 32 waves/CU (HW cap) when VGPR <= 64.
    hipLaunchKernelGGL(edgepool_kernel, dim3(2048), dim3(256), 0, stream, x, out);
}

// Round 5
// 245.852 us; speedup vs baseline: 2.2843x; 2.2843x over previous
//
#include <hip/hip_runtime.h>
#include <math.h>

// edge = a*box5(x) + b*box3(x) + c*x   (fused K5+K3 depthwise conv, zero pad)
// out  = abs(maxpool5(edge))           (maxpool pads with -inf; v-max then h-max)
// One wave (64 lanes x float4) == one full 256-px row; wave slides down a
// 16-row strip. Horizontal halo comes from OVERLAPPING neighbor loads (L1 hits),
// not shuffles, so the per-row critical chain has only vmcnt deps. Forward
// accumulation: each row scatters into 5 cyclic edge accumulators E and each
// edge row into 5 cyclic vertical-max accumulators V (40 state regs total).
// Only 4 shuffles per OUTPUT row (final horizontal 5-max), off the hot chain.
// __launch_bounds__(256,4): cap 128 VGPR — R4 showed forcing 8 waves/SIMD
// spills the rings to scratch (932 MB writes); never cap below natural need.

#define TY 16
#define STEPS (TY + 8)

typedef float vfloat4 __attribute__((ext_vector_type(4)));

__global__ __launch_bounds__(256, 4)
void edgepool_kernel(const float* __restrict__ xin, float* __restrict__ yout) {
    const int lane  = threadIdx.x & 63;
    const int wave  = threadIdx.x >> 6;
    const int blk   = blockIdx.x;                 // 0..2047
    const int plane = blk >> 2;                   // 0..511
    const int strip = ((blk & 3) << 2) | wave;    // 0..15 (4 adjacent strips/block)
    const int y0    = strip * TY;

    const float4* __restrict__ in4  = (const float4*)xin + (size_t)plane * 16384;
    vfloat4*      __restrict__ out4 = (vfloat4*)    yout + (size_t)plane * 16384;

    // lane-clamped neighbor columns (computed once; avoids OOB at image edges)
    const int nL = (lane == 0)  ? 0  : lane - 1;
    const int nR = (lane == 63) ? 63 : lane + 1;

    const float Wa = -0.01f, Wb = -0.19f, Wc = 2.2f;
    const float NINF = -INFINITY;

    float E[5][4];   // cyclic edge-row accumulators (conv partial sums)
    float V[5][4];   // cyclic vertical-5-max accumulators
#pragma unroll
    for (int k = 0; k < 5; ++k)
#pragma unroll
        for (int j = 0; j < 4; ++j) { E[k][j] = 0.f; V[k][j] = NINF; }

#pragma unroll
    for (int t = 0; t < STEPS; ++t) {
        const int  r   = y0 - 4 + t;                 // input row consumed this step
        const bool rin = (unsigned)r < 256u;
        const int  rc  = rin ? r : (r < 0 ? 0 : 255);
        const float4 vC = in4[rc * 64 + lane];
        const float4 vL = in4[rc * 64 + nL];         // same cache lines -> L1 hit
        const float4 vR = in4[rc * 64 + nR];

        const float v0 = rin ? vC.x : 0.f;
        const float v1 = rin ? vC.y : 0.f;
        const float v2 = rin ? vC.z : 0.f;
        const float v3 = rin ? vC.w : 0.f;
        const float lm2 = (rin && lane != 0)  ? vL.z : 0.f;
        const float lm1 = (rin && lane != 0)  ? vL.w : 0.f;
        const float rp0 = (rin && lane != 63) ? vR.x : 0.f;
        const float rp1 = (rin && lane != 63) ? vR.y : 0.f;

        // horizontal box sums for this row
        const float s01 = v0 + v1, s23 = v2 + v3;
        const float h3[4] = { lm1 + s01, s01 + v2, v1 + s23, s23 + rp0 };
        const float h5[4] = { lm2 + lm1 + s01 + v2, lm1 + s01 + s23,
                              s01 + s23 + rp0,      v1 + s23 + rp0 + rp1 };
        const float vv[4] = { v0, v1, v2, v3 };

        // cyclic slots (compile-time after full unroll)
        const int e2 = (t + 2) % 5, e1 = (t + 1) % 5, e0 = t % 5,
                  em1 = (t + 4) % 5, em2 = (t + 3) % 5;

        // scatter this row's contributions into the 5 live edge accumulators
#pragma unroll
        for (int j = 0; j < 4; ++j) {
            E[e2][j]  = Wa * h5[j];                                      // init row r+2
            E[e1][j]  = fmaf(Wb, h3[j], fmaf(Wa, h5[j], E[e1][j]));
            E[e0][j]  = fmaf(Wc, vv[j], fmaf(Wb, h3[j], fmaf(Wa, h5[j], E[e0][j])));
            E[em1][j] = fmaf(Wb, h3[j], fmaf(Wa, h5[j], E[em1][j]));
            E[em2][j] = fmaf(Wa, h5[j], E[em2][j]);                      // completes row r-2
        }

        // edge row er = r-2 now complete; -inf outside image for the maxpool
        const int  er  = r - 2;
        const bool ein = (unsigned)er < 256u;
        float e[4];
#pragma unroll
        for (int j = 0; j < 4; ++j) e[j] = ein ? E[em2][j] : NINF;

        // scatter edge row into the 5 live vertical-max accumulators
#pragma unroll
        for (int j = 0; j < 4; ++j) {
            V[e2][j]  = e[j];                          // init for output row er+2
            V[e1][j]  = fmaxf(V[e1][j], e[j]);
            V[e0][j]  = fmaxf(V[e0][j], e[j]);
            V[em1][j] = fmaxf(V[em1][j], e[j]);
            V[em2][j] = fmaxf(V[em2][j], e[j]);        // completes output row er-2 = r-4
        }

        // output row o = r-4: horizontal 5-max of completed V row + abs + store
        if (t >= 8) {   // compile-time predicate after unroll
            const float m0 = V[em2][0], m1 = V[em2][1], m2 = V[em2][2], m3 = V[em2][3];
            float ml2 = __shfl(m2, lane - 1, 64);
            float ml1 = __shfl(m3, lane - 1, 64);
            float mr0 = __shfl(m0, lane + 1, 64);
            float mr1 = __shfl(m1, lane + 1, 64);
            ml2 = (lane == 0)  ? NINF : ml2;
            ml1 = (lane == 0)  ? NINF : ml1;
            mr0 = (lane == 63) ? NINF : mr0;
            mr1 = (lane == 63) ? NINF : mr1;
            vfloat4 ov;
            ov.x = fabsf(fmaxf(fmaxf(ml2, ml1), fmaxf(fmaxf(m0, m1), m2)));
            ov.y = fabsf(fmaxf(fmaxf(ml1, m0), fmaxf(fmaxf(m1, m2), m3)));
            ov.z = fabsf(fmaxf(fmaxf(m0, m1), fmaxf(fmaxf(m2, m3), mr0)));
            ov.w = fabsf(fmaxf(fmaxf(m1, m2), fmaxf(fmaxf(m3, mr0), mr1)));
            __builtin_nontemporal_store(ov, &out4[(r - 4) * 64 + lane]);
        }
    }
}

extern "C" void kernel_launch(void* const* d_in, const int* in_sizes, int n_in,
                              void* d_out, int out_size, void* d_ws, size_t ws_size,
                              hipStream_t stream) {
    const float* x   = (const float*)d_in[0];
    float*       out = (float*)d_out;
    // 512 planes x 16 strips = 8192 wave-tasks; 4 waves/block -> 2048 blocks.
    hipLaunchKernelGGL(edgepool_kernel, dim3(2048), dim3(256), 0, stream, x, out);
}

// Round 6
// 231.433 us; speedup vs baseline: 2.4266x; 1.0623x over previous
//
#include <hip/hip_runtime.h>
#include <math.h>

// edge = a*box5(x) + b*box3(x) + c*x   (fused K5+K3 depthwise conv, zero pad)
// out  = abs(maxpool5(edge))           (maxpool pads with -inf; v-max then h-max)
// Two-phase wave: (1) burst-load ALL 16 rows of the strip into registers
// (16 KB in flight -> deep MLP, counted-vmcnt pipeline), (2) compute sweep
// with shuffle halo + forward accumulation into 5 cyclic edge accumulators E
// and 5 cyclic vertical-max accumulators V. Only lgkm (shuffle) waits in the
// sweep. TY=8: 512 planes x 32 strips = 4096 blocks; adjacent waves own
// adjacent strips so halo rows hit L1/L2.
// __launch_bounds__(256,4): VGPR cap 128 >= natural need (~120). R4 lesson:
// never cap below need (spills showed as WRITE_SIZE 932 MB).

#define TY 8
#define STEPS (TY + 8)

typedef float vfloat4 __attribute__((ext_vector_type(4)));

__global__ __launch_bounds__(256, 4)
void edgepool_kernel(const float* __restrict__ xin, float* __restrict__ yout) {
    const int lane  = threadIdx.x & 63;
    const int wave  = threadIdx.x >> 6;
    const int blk   = blockIdx.x;                 // 0..4095
    const int plane = blk >> 3;                   // 0..511
    const int strip = ((blk & 7) << 2) | wave;    // 0..31 (adjacent strips/block)
    const int y0    = strip * TY;

    const float4* __restrict__ in4  = (const float4*)xin + (size_t)plane * 16384;
    vfloat4*      __restrict__ out4 = (vfloat4*)    yout + (size_t)plane * 16384;

    const float Wa = -0.01f, Wb = -0.19f, Wc = 2.2f;
    const float NINF = -INFINITY;

    // ---- phase 1: burst-load the whole strip (rows y0-4 .. y0+11) ----
    float4 pf[STEPS];
#pragma unroll
    for (int t = 0; t < STEPS; ++t) {
        const int r  = y0 - 4 + t;
        const int rc = (r < 0) ? 0 : (r > 255 ? 255 : r);   // clamped; zeroed at use
        pf[t] = in4[rc * 64 + lane];
    }

    float E[5][4];   // cyclic edge-row accumulators (conv partial sums)
    float V[5][4];   // cyclic vertical-5-max accumulators
#pragma unroll
    for (int k = 0; k < 5; ++k)
#pragma unroll
        for (int j = 0; j < 4; ++j) { E[k][j] = 0.f; V[k][j] = NINF; }

    // ---- phase 2: compute sweep (consumes pf[t] in order) ----
#pragma unroll
    for (int t = 0; t < STEPS; ++t) {
        const int  r   = y0 - 4 + t;
        const bool rin = (unsigned)r < 256u;
        const float v0 = rin ? pf[t].x : 0.f;
        const float v1 = rin ? pf[t].y : 0.f;
        const float v2 = rin ? pf[t].z : 0.f;
        const float v3 = rin ? pf[t].w : 0.f;

        // horizontal halo from neighbor lanes (zero-pad image edges)
        float lm2 = __shfl(v2, lane - 1, 64);
        float lm1 = __shfl(v3, lane - 1, 64);
        float rp0 = __shfl(v0, lane + 1, 64);
        float rp1 = __shfl(v1, lane + 1, 64);
        lm2 = (lane == 0)  ? 0.f : lm2;
        lm1 = (lane == 0)  ? 0.f : lm1;
        rp0 = (lane == 63) ? 0.f : rp0;
        rp1 = (lane == 63) ? 0.f : rp1;

        // horizontal box sums for this row
        const float s01 = v0 + v1, s23 = v2 + v3;
        const float h3[4] = { lm1 + s01, s01 + v2, v1 + s23, s23 + rp0 };
        const float h5[4] = { lm2 + lm1 + s01 + v2, lm1 + s01 + s23,
                              s01 + s23 + rp0,      v1 + s23 + rp0 + rp1 };
        const float vv[4] = { v0, v1, v2, v3 };

        // cyclic slots (compile-time after full unroll)
        const int e2 = (t + 2) % 5, e1 = (t + 1) % 5, e0 = t % 5,
                  em1 = (t + 4) % 5, em2 = (t + 3) % 5;

        // scatter this row's contributions into the 5 live edge accumulators
#pragma unroll
        for (int j = 0; j < 4; ++j) {
            E[e2][j]  = Wa * h5[j];                                      // init row r+2
            E[e1][j]  = fmaf(Wb, h3[j], fmaf(Wa, h5[j], E[e1][j]));
            E[e0][j]  = fmaf(Wc, vv[j], fmaf(Wb, h3[j], fmaf(Wa, h5[j], E[e0][j])));
            E[em1][j] = fmaf(Wb, h3[j], fmaf(Wa, h5[j], E[em1][j]));
            E[em2][j] = fmaf(Wa, h5[j], E[em2][j]);                      // completes row r-2
        }

        // edge row er = r-2 complete; -inf outside image for the maxpool
        const int  er  = r - 2;
        const bool ein = (unsigned)er < 256u;
        float e[4];
#pragma unroll
        for (int j = 0; j < 4; ++j) e[j] = ein ? E[em2][j] : NINF;

        // scatter edge row into the 5 live vertical-max accumulators
#pragma unroll
        for (int j = 0; j < 4; ++j) {
            V[e2][j]  = e[j];                          // init for output row er+2
            V[e1][j]  = fmaxf(V[e1][j], e[j]);
            V[e0][j]  = fmaxf(V[e0][j], e[j]);
            V[em1][j] = fmaxf(V[em1][j], e[j]);
            V[em2][j] = fmaxf(V[em2][j], e[j]);        // completes output row r-4
        }

        // output row o = r-4: horizontal 5-max of completed V row + abs + store
        if (t >= 8) {   // compile-time predicate after unroll
            const float m0 = V[em2][0], m1 = V[em2][1], m2 = V[em2][2], m3 = V[em2][3];
            float ml2 = __shfl(m2, lane - 1, 64);
            float ml1 = __shfl(m3, lane - 1, 64);
            float mr0 = __shfl(m0, lane + 1, 64);
            float mr1 = __shfl(m1, lane + 1, 64);
            ml2 = (lane == 0)  ? NINF : ml2;
            ml1 = (lane == 0)  ? NINF : ml1;
            mr0 = (lane == 63) ? NINF : mr0;
            mr1 = (lane == 63) ? NINF : mr1;
            vfloat4 ov;
            ov.x = fabsf(fmaxf(fmaxf(ml2, ml1), fmaxf(fmaxf(m0, m1), m2)));
            ov.y = fabsf(fmaxf(fmaxf(ml1, m0), fmaxf(fmaxf(m1, m2), m3)));
            ov.z = fabsf(fmaxf(fmaxf(m0, m1), fmaxf(fmaxf(m2, m3), mr0)));
            ov.w = fabsf(fmaxf(fmaxf(m1, m2), fmaxf(fmaxf(m3, mr0), mr1)));
            __builtin_nontemporal_store(ov, &out4[(r - 4) * 64 + lane]);
        }
    }
}

extern "C" void kernel_launch(void* const* d_in, const int* in_sizes, int n_in,
                              void* d_out, int out_size, void* d_ws, size_t ws_size,
                              hipStream_t stream) {
    const float* x   = (const float*)d_in[0];
    float*       out = (float*)d_out;
    // 512 planes x 32 strips / 4 waves-per-block = 4096 blocks.
    hipLaunchKernelGGL(edgepool_kernel, dim3(4096), dim3(256), 0, stream, x, out);
}